// Round 1
// baseline (91.576 us; speedup 1.0000x reference)
//
#include <hip/hip_runtime.h>

#define NN 4096
#define HID 128
#define CAP 256
#define THRV 0.99f

// ---------------- adjacency build: per-row u16 neighbor lists ----------------
__global__ __launch_bounds__(256) void build_adj(const float* __restrict__ A,
                                                 int* __restrict__ cnt,
                                                 unsigned short* __restrict__ nbr) {
  int row = blockIdx.x;
  __shared__ int sc;
  __shared__ unsigned short sn[CAP];
  if (threadIdx.x == 0) sc = 0;
  __syncthreads();
  const float4* Arow = (const float4*)(A + (size_t)row * NN);
#pragma unroll
  for (int it = 0; it < 4; ++it) {
    int j4 = it * 256 + threadIdx.x;   // 0..1023
    float4 v = Arow[j4];
    int j = j4 * 4;
    if (v.x > THRV) { int p = atomicAdd(&sc, 1); if (p < CAP) sn[p] = (unsigned short)(j); }
    if (v.y > THRV) { int p = atomicAdd(&sc, 1); if (p < CAP) sn[p] = (unsigned short)(j + 1); }
    if (v.z > THRV) { int p = atomicAdd(&sc, 1); if (p < CAP) sn[p] = (unsigned short)(j + 2); }
    if (v.w > THRV) { int p = atomicAdd(&sc, 1); if (p < CAP) sn[p] = (unsigned short)(j + 3); }
  }
  __syncthreads();
  int c = min(sc, CAP);
  if (threadIdx.x == 0) cnt[row] = c;
  for (int k = threadIdx.x; k < c; k += 256) nbr[(size_t)row * CAP + k] = sn[k];
}

// ---------------- f32 GEMM: C[M,128] = X[M,K] @ W[K,128] + b (opt. relu) ----
// BM=64, BN=64 (blockIdx.y), BK=16, 256 threads, 4x4 acc/thread.
// blockIdx.z selects one of two (W, b, out, relu) sets (dual-output launch).
__global__ __launch_bounds__(256) void gemm_n128(
    const float* __restrict__ X, int M, int K,
    const float* __restrict__ W0, const float* __restrict__ b0, float* __restrict__ o0, int r0,
    const float* __restrict__ W1, const float* __restrict__ b1, float* __restrict__ o1, int r1) {
  const float* W; const float* bias; float* out; int dorelu;
  if (blockIdx.z == 0) { W = W0; bias = b0; out = o0; dorelu = r0; }
  else                 { W = W1; bias = b1; out = o1; dorelu = r1; }

  __shared__ float As[16][68];
  __shared__ float Bs[16][68];

  const int tid  = threadIdx.x;
  const int row0 = blockIdx.x * 64;
  const int col0 = blockIdx.y * 64;
  const int ty = tid >> 4;   // 0..15 row group
  const int tx = tid & 15;   // 0..15 col group

  const int la_m = tid >> 2;        // 0..63  A-tile row
  const int la_k = (tid & 3) * 4;   // k offset {0,4,8,12}
  const int lb_k = tid >> 4;        // 0..15  B-tile k
  const int lb_n = (tid & 15) * 4;  // 0..60  B-tile col

  float acc[4][4] = {};

  for (int kk = 0; kk < K; kk += 16) {
    float4 av = *(const float4*)(X + (size_t)(row0 + la_m) * K + kk + la_k);
    As[la_k + 0][la_m] = av.x;
    As[la_k + 1][la_m] = av.y;
    As[la_k + 2][la_m] = av.z;
    As[la_k + 3][la_m] = av.w;
    float4 bv = *(const float4*)(W + (size_t)(kk + lb_k) * 128 + col0 + lb_n);
    *(float4*)(&Bs[lb_k][lb_n]) = bv;
    __syncthreads();
#pragma unroll
    for (int k = 0; k < 16; ++k) {
      float4 a = *(const float4*)(&As[k][ty * 4]);
      float4 b = *(const float4*)(&Bs[k][tx * 4]);
      float ar[4] = {a.x, a.y, a.z, a.w};
      float br[4] = {b.x, b.y, b.z, b.w};
#pragma unroll
      for (int i = 0; i < 4; ++i)
#pragma unroll
        for (int j = 0; j < 4; ++j)
          acc[i][j] = fmaf(ar[i], br[j], acc[i][j]);
    }
    __syncthreads();
  }

#pragma unroll
  for (int i = 0; i < 4; ++i) {
    int r = row0 + ty * 4 + i;
    float4 v;
    float* vp = (float*)&v;
#pragma unroll
    for (int j = 0; j < 4; ++j) {
      int c = col0 + tx * 4 + j;
      float t = acc[i][j] + bias[c];
      if (dorelu) t = fmaxf(t, 0.f);
      vp[j] = t;
    }
    *(float4*)(out + (size_t)r * 128 + col0 + tx * 4) = v;
  }
}

// ---------------- neighbor max-pool over scores ----------------
__global__ __launch_bounds__(128) void maxpool(const int* __restrict__ cnt,
                                               const unsigned short* __restrict__ nbr,
                                               const float* __restrict__ scores,
                                               float* __restrict__ pooled) {
  int row = blockIdx.x;
  __shared__ unsigned short sn[CAP];
  int c = cnt[row];
  for (int k = threadIdx.x; k < c; k += 128) sn[k] = nbr[(size_t)row * CAP + k];
  __syncthreads();
  // scores >= 0 (relu), empty set -> 0, so init 0 is exact.
  float v0 = 0.f, v1 = 0.f, v2 = 0.f, v3 = 0.f;
  int k = 0;
  for (; k + 4 <= c; k += 4) {
    int j0 = sn[k], j1 = sn[k + 1], j2 = sn[k + 2], j3 = sn[k + 3];
    v0 = fmaxf(v0, scores[(size_t)j0 * HID + threadIdx.x]);
    v1 = fmaxf(v1, scores[(size_t)j1 * HID + threadIdx.x]);
    v2 = fmaxf(v2, scores[(size_t)j2 * HID + threadIdx.x]);
    v3 = fmaxf(v3, scores[(size_t)j3 * HID + threadIdx.x]);
  }
  for (; k < c; ++k) v0 = fmaxf(v0, scores[(size_t)sn[k] * HID + threadIdx.x]);
  pooled[(size_t)row * HID + threadIdx.x] = fmaxf(fmaxf(v0, v1), fmaxf(v2, v3));
}

// ---------------- relu + concat + L2 row-normalize ----------------
// 256 threads = 4 waves, one row per wave; each lane holds 2 floats per half.
__global__ __launch_bounds__(256) void normcat(const float* __restrict__ S,
                                               const float* __restrict__ P2,
                                               float* __restrict__ xout) {
  int row  = blockIdx.x * 4 + (threadIdx.x >> 6);
  int lane = threadIdx.x & 63;
  float2 a = ((const float2*)S)[(size_t)row * 64 + lane];
  float2 b = ((const float2*)P2)[(size_t)row * 64 + lane];
  a.x = fmaxf(a.x, 0.f); a.y = fmaxf(a.y, 0.f);
  b.x = fmaxf(b.x, 0.f); b.y = fmaxf(b.y, 0.f);
  float ss = a.x * a.x + a.y * a.y + b.x * b.x + b.y * b.y;
#pragma unroll
  for (int off = 32; off >= 1; off >>= 1) ss += __shfl_xor(ss, off, 64);
  float scale = 1.0f / fmaxf(sqrtf(ss), 1e-12f);
  ((float2*)xout)[(size_t)row * 128 + lane]      = make_float2(a.x * scale, a.y * scale);
  ((float2*)xout)[(size_t)row * 128 + 64 + lane] = make_float2(b.x * scale, b.y * scale);
}

extern "C" void kernel_launch(void* const* d_in, const int* in_sizes, int n_in,
                              void* d_out, int out_size, void* d_ws, size_t ws_size,
                              hipStream_t stream) {
  (void)in_sizes; (void)n_in; (void)out_size; (void)ws_size;
  const float* x   = (const float*)d_in[0];
  const float* A   = (const float*)d_in[1];
  const float* Wp0 = (const float*)d_in[2];
  const float* bp0 = (const float*)d_in[3];
  const float* Ws0 = (const float*)d_in[4];
  const float* bs0 = (const float*)d_in[5];
  const float* Wn0 = (const float*)d_in[6];
  const float* bn0 = (const float*)d_in[7];
  const float* Wp1 = (const float*)d_in[8];
  const float* bp1 = (const float*)d_in[9];
  const float* Ws1 = (const float*)d_in[10];
  const float* bs1 = (const float*)d_in[11];
  const float* Wn1 = (const float*)d_in[12];
  const float* bn1 = (const float*)d_in[13];

  char* ws = (char*)d_ws;
  int* cnt             = (int*)ws;            ws += (size_t)NN * 4;
  unsigned short* nbr  = (unsigned short*)ws; ws += (size_t)NN * CAP * 2;
  float* scores        = (float*)ws;          ws += (size_t)NN * HID * 4;
  float* S             = (float*)ws;          ws += (size_t)NN * HID * 4;
  float* pooled        = (float*)ws;          ws += (size_t)NN * HID * 4;
  float* xbuf          = (float*)ws;          ws += (size_t)NN * 256 * 4;
  float* P2 = scores;  // scores dead after maxpool; reuse

  build_adj<<<NN, 256, 0, stream>>>(A, cnt, nbr);

  const float* Xin = x;
  float* Xout = xbuf;
  const float *Wp = Wp0, *bp = bp0, *Wss = Ws0, *bs = bs0, *Wn = Wn0, *bn = bn0;
  for (int layer = 0; layer < 2; ++layer) {
    gemm_n128<<<dim3(64, 2, 2), 256, 0, stream>>>(Xin, NN, 256,
        Wp, bp, scores, 1,
        Wss, bs, S, 0);
    maxpool<<<NN, 128, 0, stream>>>(cnt, nbr, scores, pooled);
    gemm_n128<<<dim3(64, 2, 1), 256, 0, stream>>>(pooled, NN, 128,
        Wn, bn, P2, 0,
        Wn, bn, P2, 0);
    normcat<<<NN / 4, 256, 0, stream>>>(S, P2, Xout);
    Xin = xbuf; Xout = (float*)d_out;
    Wp = Wp1; bp = bp1; Wss = Ws1; bs = bs1; Wn = Wn1; bn = bn1;
  }
}

// Round 2
// 82.623 us; speedup vs baseline: 1.1084x; 1.1084x over previous
//
#include <hip/hip_runtime.h>

#define NN 4096
#define HID 128
#define CAP 256
#define THRV 0.99f

typedef __attribute__((ext_vector_type(8))) short short8v;
typedef __attribute__((ext_vector_type(4))) float f32x4;

__device__ inline unsigned short f2bf(float f) {
  unsigned u = __builtin_bit_cast(unsigned, f);
  u = (u + 0x7fffu + ((u >> 16) & 1u)) >> 16;   // RNE
  return (unsigned short)u;
}

// ---------- adjacency build (rows 0..NN-1) + weight bf16-transpose prep ----------
__global__ __launch_bounds__(256) void adj_prep(
    const float* __restrict__ A, int* __restrict__ cnt, unsigned short* __restrict__ nbr,
    const float* __restrict__ w0, const float* __restrict__ w1, const float* __restrict__ w2,
    const float* __restrict__ w3, const float* __restrict__ w4, const float* __restrict__ w5,
    unsigned short* __restrict__ t0, unsigned short* __restrict__ t1, unsigned short* __restrict__ t2,
    unsigned short* __restrict__ t3, unsigned short* __restrict__ t4, unsigned short* __restrict__ t5) {
  int bid = blockIdx.x;
  if (bid >= NN) {
    // weight prep: W[k][128] f32 -> Wt[n][K] bf16
    int id = bid - NN;
    int m = id >> 7, blk = id & 127;
    const float* src; unsigned short* dst; int K;
    switch (m) {
      case 0: src = w0; dst = t0; K = 256; break;
      case 1: src = w1; dst = t1; K = 256; break;
      case 2: src = w2; dst = t2; K = 128; break;
      case 3: src = w3; dst = t3; K = 256; break;
      case 4: src = w4; dst = t4; K = 256; break;
      default: src = w5; dst = t5; K = 128; break;
    }
    int e = blk * 256 + threadIdx.x;
    if (e < K * 128) {
      int k = e >> 7, n = e & 127;
      dst[n * K + k] = f2bf(src[e]);
    }
    return;
  }
  int row = bid;
  __shared__ int sc;
  __shared__ unsigned short sn[CAP];
  if (threadIdx.x == 0) sc = 0;
  __syncthreads();
  const float4* Arow = (const float4*)(A + (size_t)row * NN);
#pragma unroll
  for (int it = 0; it < 4; ++it) {
    int j4 = it * 256 + threadIdx.x;
    float4 v = Arow[j4];
    int j = j4 * 4;
    if (v.x > THRV) { int p = atomicAdd(&sc, 1); if (p < CAP) sn[p] = (unsigned short)(j); }
    if (v.y > THRV) { int p = atomicAdd(&sc, 1); if (p < CAP) sn[p] = (unsigned short)(j + 1); }
    if (v.z > THRV) { int p = atomicAdd(&sc, 1); if (p < CAP) sn[p] = (unsigned short)(j + 2); }
    if (v.w > THRV) { int p = atomicAdd(&sc, 1); if (p < CAP) sn[p] = (unsigned short)(j + 3); }
  }
  __syncthreads();
  int c = min(sc, CAP);
  if (threadIdx.x == 0) cnt[row] = c;
  for (int k = threadIdx.x; k < c; k += 256) nbr[(size_t)row * CAP + k] = sn[k];
}

// ---------- MFMA GEMM: out[4096,128] = X[4096,K] @ Wt^T + b, dual weight-set via z ----
// 1 wave/block, 16 rows/block, full N=128 (8 nfrags), no LDS: frags straight from L2.
// obf: 1 -> relu + bf16 store (scores); 0 -> f32 store (S).
template<bool ABF16>
__global__ __launch_bounds__(64) void gemm16(
    const void* __restrict__ Xv, int K,
    const unsigned short* __restrict__ Wt0, const float* __restrict__ b0, void* __restrict__ o0, int bf0,
    const unsigned short* __restrict__ Wt1, const float* __restrict__ b1, void* __restrict__ o1, int bf1) {
  const unsigned short* Wt; const float* bias; void* out; int obf;
  if (blockIdx.z == 0) { Wt = Wt0; bias = b0; out = o0; obf = bf0; }
  else                 { Wt = Wt1; bias = b1; out = o1; obf = bf1; }
  const int lane = threadIdx.x;
  const int g = lane >> 4, r15 = lane & 15;
  const int row = blockIdx.x * 16 + r15;
  f32x4 acc[8] = {};
  const float* Xf = (const float*)Xv;
  const unsigned short* Xh = (const unsigned short*)Xv;

  for (int kt = 0; kt < K; kt += 32) {
    short8v a;
    if (ABF16) {
      const unsigned short* p = Xh + (size_t)row * K + kt + 4 * g;
      short4 lo = *(const short4*)p;
      short4 hi = *(const short4*)(p + 16);
      a[0] = lo.x; a[1] = lo.y; a[2] = lo.z; a[3] = lo.w;
      a[4] = hi.x; a[5] = hi.y; a[6] = hi.z; a[7] = hi.w;
    } else {
      const float* p = Xf + (size_t)row * K + kt + 4 * g;
      float4 lo = *(const float4*)p;
      float4 hi = *(const float4*)(p + 16);
      a[0] = (short)f2bf(lo.x); a[1] = (short)f2bf(lo.y);
      a[2] = (short)f2bf(lo.z); a[3] = (short)f2bf(lo.w);
      a[4] = (short)f2bf(hi.x); a[5] = (short)f2bf(hi.y);
      a[6] = (short)f2bf(hi.z); a[7] = (short)f2bf(hi.w);
    }
    const unsigned short* wbase = Wt + (size_t)r15 * K + kt + 4 * g;
#pragma unroll
    for (int nf = 0; nf < 8; ++nf) {
      const unsigned short* q = wbase + (size_t)(nf * 16) * K;
      short4 lo = *(const short4*)q;
      short4 hi = *(const short4*)(q + 16);
      short8v b;
      b[0] = lo.x; b[1] = lo.y; b[2] = lo.z; b[3] = lo.w;
      b[4] = hi.x; b[5] = hi.y; b[6] = hi.z; b[7] = hi.w;
      acc[nf] = __builtin_amdgcn_mfma_f32_16x16x32_bf16(a, b, acc[nf], 0, 0, 0);
    }
  }
#pragma unroll
  for (int nf = 0; nf < 8; ++nf) {
    int col = nf * 16 + r15;
    float bv = bias[col];
#pragma unroll
    for (int r = 0; r < 4; ++r) {
      int orow = blockIdx.x * 16 + 4 * g + r;
      float t = acc[nf][r] + bv;
      if (obf) {
        t = fmaxf(t, 0.f);
        ((unsigned short*)out)[(size_t)orow * 128 + col] = f2bf(t);
      } else {
        ((float*)out)[(size_t)orow * 128 + col] = t;
      }
    }
  }
}

// ---------- neighbor max-pool on non-negative bf16 (integer max on bit patterns) ----
__global__ __launch_bounds__(128) void maxpool(const int* __restrict__ cnt,
                                               const unsigned short* __restrict__ nbr,
                                               const unsigned short* __restrict__ sc,
                                               unsigned short* __restrict__ pooled) {
  int row = blockIdx.x;
  __shared__ unsigned short sn[CAP];
  int c = cnt[row];
  for (int k = threadIdx.x; k < c; k += 128) sn[k] = nbr[(size_t)row * CAP + k];
  __syncthreads();
  unsigned v0 = 0, v1 = 0, v2 = 0, v3 = 0;
  int k = 0;
  for (; k + 4 <= c; k += 4) {
    unsigned a0 = sc[(size_t)sn[k] * HID + threadIdx.x];
    unsigned a1 = sc[(size_t)sn[k + 1] * HID + threadIdx.x];
    unsigned a2 = sc[(size_t)sn[k + 2] * HID + threadIdx.x];
    unsigned a3 = sc[(size_t)sn[k + 3] * HID + threadIdx.x];
    v0 = v0 > a0 ? v0 : a0; v1 = v1 > a1 ? v1 : a1;
    v2 = v2 > a2 ? v2 : a2; v3 = v3 > a3 ? v3 : a3;
  }
  for (; k < c; ++k) { unsigned a = sc[(size_t)sn[k] * HID + threadIdx.x]; v0 = v0 > a ? v0 : a; }
  unsigned v = v0 > v1 ? v0 : v1; unsigned w = v2 > v3 ? v2 : v3;
  v = v > w ? v : w;
  pooled[(size_t)row * HID + threadIdx.x] = (unsigned short)v;
}

// ---------- pooled@Wn + bn, fused with relu + concat(S,.) + row L2-normalize ----------
// OBF16: write bf16 x for next layer; else f32 to d_out.
template<bool OBF16>
__global__ __launch_bounds__(64) void gemm_pool_norm(
    const unsigned short* __restrict__ P, const unsigned short* __restrict__ Wt,
    const float* __restrict__ bn, const float* __restrict__ S, void* __restrict__ xout) {
  const int K = 128;
  const int lane = threadIdx.x;
  const int g = lane >> 4, r15 = lane & 15;
  const int row = blockIdx.x * 16 + r15;
  f32x4 acc[8] = {};
#pragma unroll
  for (int kt = 0; kt < K; kt += 32) {
    const unsigned short* p = P + (size_t)row * K + kt + 4 * g;
    short4 lo = *(const short4*)p;
    short4 hi = *(const short4*)(p + 16);
    short8v a;
    a[0] = lo.x; a[1] = lo.y; a[2] = lo.z; a[3] = lo.w;
    a[4] = hi.x; a[5] = hi.y; a[6] = hi.z; a[7] = hi.w;
    const unsigned short* wbase = Wt + (size_t)r15 * K + kt + 4 * g;
#pragma unroll
    for (int nf = 0; nf < 8; ++nf) {
      const unsigned short* q = wbase + (size_t)(nf * 16) * K;
      short4 blo = *(const short4*)q;
      short4 bhi = *(const short4*)(q + 16);
      short8v b;
      b[0] = blo.x; b[1] = blo.y; b[2] = blo.z; b[3] = blo.w;
      b[4] = bhi.x; b[5] = bhi.y; b[6] = bhi.z; b[7] = bhi.w;
      acc[nf] = __builtin_amdgcn_mfma_f32_16x16x32_bf16(a, b, acc[nf], 0, 0, 0);
    }
  }
  // bias + relu on pool half
#pragma unroll
  for (int nf = 0; nf < 8; ++nf) {
    float bv = bn[nf * 16 + r15];
#pragma unroll
    for (int r = 0; r < 4; ++r) acc[nf][r] = fmaxf(acc[nf][r] + bv, 0.f);
  }
#pragma unroll
  for (int r = 0; r < 4; ++r) {
    int orow = blockIdx.x * 16 + 4 * g + r;
    // pool-half sum of squares for row orow (lanes of this 16-group hold its cols)
    float ss = 0.f;
#pragma unroll
    for (int nf = 0; nf < 8; ++nf) ss += acc[nf][r] * acc[nf][r];
#pragma unroll
    for (int off = 1; off < 16; off <<= 1) ss += __shfl_xor(ss, off, 16);
    // self half: relu + sumsq (16 lanes x 8 f32 = 128)
    float4 sa = *(const float4*)(S + (size_t)orow * 128 + r15 * 8);
    float4 sb = *(const float4*)(S + (size_t)orow * 128 + r15 * 8 + 4);
    sa.x = fmaxf(sa.x, 0.f); sa.y = fmaxf(sa.y, 0.f); sa.z = fmaxf(sa.z, 0.f); sa.w = fmaxf(sa.w, 0.f);
    sb.x = fmaxf(sb.x, 0.f); sb.y = fmaxf(sb.y, 0.f); sb.z = fmaxf(sb.z, 0.f); sb.w = fmaxf(sb.w, 0.f);
    float s2 = sa.x * sa.x + sa.y * sa.y + sa.z * sa.z + sa.w * sa.w
             + sb.x * sb.x + sb.y * sb.y + sb.z * sb.z + sb.w * sb.w;
#pragma unroll
    for (int off = 1; off < 16; off <<= 1) s2 += __shfl_xor(s2, off, 16);
    float scale = 1.0f / fmaxf(sqrtf(ss + s2), 1e-12f);
    // write self half: cols r15*8 .. +8
    if (OBF16) {
      unsigned short* o = (unsigned short*)xout;
      unsigned short h[8] = { f2bf(sa.x * scale), f2bf(sa.y * scale), f2bf(sa.z * scale), f2bf(sa.w * scale),
                              f2bf(sb.x * scale), f2bf(sb.y * scale), f2bf(sb.z * scale), f2bf(sb.w * scale) };
      uint4 wv;
      wv.x = (unsigned)h[0] | ((unsigned)h[1] << 16);
      wv.y = (unsigned)h[2] | ((unsigned)h[3] << 16);
      wv.z = (unsigned)h[4] | ((unsigned)h[5] << 16);
      wv.w = (unsigned)h[6] | ((unsigned)h[7] << 16);
      *(uint4*)(o + (size_t)orow * 256 + r15 * 8) = wv;
#pragma unroll
      for (int nf = 0; nf < 8; ++nf)
        o[(size_t)orow * 256 + 128 + nf * 16 + r15] = f2bf(acc[nf][r] * scale);
    } else {
      float* o = (float*)xout;
      float4 wa = make_float4(sa.x * scale, sa.y * scale, sa.z * scale, sa.w * scale);
      float4 wb = make_float4(sb.x * scale, sb.y * scale, sb.z * scale, sb.w * scale);
      *(float4*)(o + (size_t)orow * 256 + r15 * 8) = wa;
      *(float4*)(o + (size_t)orow * 256 + r15 * 8 + 4) = wb;
#pragma unroll
      for (int nf = 0; nf < 8; ++nf)
        o[(size_t)orow * 256 + 128 + nf * 16 + r15] = acc[nf][r] * scale;
    }
  }
}

extern "C" void kernel_launch(void* const* d_in, const int* in_sizes, int n_in,
                              void* d_out, int out_size, void* d_ws, size_t ws_size,
                              hipStream_t stream) {
  (void)in_sizes; (void)n_in; (void)out_size; (void)ws_size;
  const float* x   = (const float*)d_in[0];
  const float* A   = (const float*)d_in[1];
  const float* Wp0 = (const float*)d_in[2];
  const float* bp0 = (const float*)d_in[3];
  const float* Ws0 = (const float*)d_in[4];
  const float* bs0 = (const float*)d_in[5];
  const float* Wn0 = (const float*)d_in[6];
  const float* bn0 = (const float*)d_in[7];
  const float* Wp1 = (const float*)d_in[8];
  const float* bp1 = (const float*)d_in[9];
  const float* Ws1 = (const float*)d_in[10];
  const float* bs1 = (const float*)d_in[11];
  const float* Wn1 = (const float*)d_in[12];
  const float* bn1 = (const float*)d_in[13];

  char* ws = (char*)d_ws;
  auto alloc = [&](size_t bytes) { char* p = ws; ws += (bytes + 255) & ~(size_t)255; return p; };
  int* cnt            = (int*)alloc((size_t)NN * 4);
  unsigned short* nbr = (unsigned short*)alloc((size_t)NN * CAP * 2);
  unsigned short* tWp0 = (unsigned short*)alloc(256 * 128 * 2);
  unsigned short* tWs0 = (unsigned short*)alloc(256 * 128 * 2);
  unsigned short* tWn0 = (unsigned short*)alloc(128 * 128 * 2);
  unsigned short* tWp1 = (unsigned short*)alloc(256 * 128 * 2);
  unsigned short* tWs1 = (unsigned short*)alloc(256 * 128 * 2);
  unsigned short* tWn1 = (unsigned short*)alloc(128 * 128 * 2);
  unsigned short* scores = (unsigned short*)alloc((size_t)NN * 128 * 2);
  float* S            = (float*)alloc((size_t)NN * 128 * 4);
  unsigned short* pooled = (unsigned short*)alloc((size_t)NN * 128 * 2);
  unsigned short* xb16 = (unsigned short*)alloc((size_t)NN * 256 * 2);

  adj_prep<<<NN + 6 * 128, 256, 0, stream>>>(A, cnt, nbr,
      Wp0, Ws0, Wn0, Wp1, Ws1, Wn1,
      tWp0, tWs0, tWn0, tWp1, tWs1, tWn1);

  // ---- layer 0 (A = f32 x) ----
  gemm16<false><<<dim3(NN / 16, 1, 2), 64, 0, stream>>>(x, 256,
      tWp0, bp0, scores, 1,
      tWs0, bs0, S, 0);
  maxpool<<<NN, 128, 0, stream>>>(cnt, nbr, scores, pooled);
  gemm_pool_norm<true><<<NN / 16, 64, 0, stream>>>(pooled, tWn0, bn0, S, xb16);

  // ---- layer 1 (A = bf16 xb16) ----
  gemm16<true><<<dim3(NN / 16, 1, 2), 64, 0, stream>>>(xb16, 256,
      tWp1, bp1, scores, 1,
      tWs1, bs1, S, 0);
  maxpool<<<NN, 128, 0, stream>>>(cnt, nbr, scores, pooled);
  gemm_pool_norm<false><<<NN / 16, 64, 0, stream>>>(pooled, tWn1, bn1, S, d_out);
}

// Round 3
// 75.735 us; speedup vs baseline: 1.2092x; 1.0909x over previous
//
#include <hip/hip_runtime.h>

#define NN 4096
#define CAP 256
#define THRV 0.99f

typedef __attribute__((ext_vector_type(8))) short short8v;
typedef __attribute__((ext_vector_type(4))) float f32x4;

__device__ inline unsigned short f2bf(float f) {
  unsigned u = __builtin_bit_cast(unsigned, f);
  u = (u + 0x7fffu + ((u >> 16) & 1u)) >> 16;   // RNE
  return (unsigned short)u;
}
__device__ inline unsigned maxu16x2(unsigned a, unsigned b) {
  unsigned lo = ((a & 0xffffu) > (b & 0xffffu)) ? (a & 0xffffu) : (b & 0xffffu);
  unsigned hi = ((a >> 16) > (b >> 16)) ? (a & 0xffff0000u) : (b & 0xffff0000u);
  return hi | lo;
}

// Packed fragment layout for bf16 weights: frag(ktIdx,nf) is 512 bf16 (1KB),
// element addr = ((ktIdx*8 + nf)*512) + lane*8 + elem, lane = g*16 + (n&15),
// elem = (k&3) + 4*((k>>4)&1), g = (k>>2)&3.  One uint4/lane per MFMA B-frag.

// ================= K1: layer-0 dual GEMM (f32 W direct) + weight prep =======
__global__ __launch_bounds__(256) void k1(
    const float* __restrict__ x,
    const float* __restrict__ Wp0, const float* __restrict__ bp0,
    const float* __restrict__ Ws0, const float* __restrict__ bs0,
    const float* __restrict__ Wn0, const float* __restrict__ Wp1,
    const float* __restrict__ Ws1, const float* __restrict__ Wn1,
    unsigned short* __restrict__ scores0, float* __restrict__ S0,
    unsigned short* __restrict__ tWn0, unsigned short* __restrict__ tWp1,
    unsigned short* __restrict__ tWs1, unsigned short* __restrict__ tWn1) {
  const int bid = blockIdx.x;
  if (bid >= 128) {
    // ---- weight prep into packed-fragment bf16 layout ----
    int id = bid - 128;
    const float* src; unsigned short* dst; int base;
    if (id < 16)      { src = Wn0; dst = tWn0; base = id; }
    else if (id < 48) { src = Wp1; dst = tWp1; base = id - 16; }
    else if (id < 80) { src = Ws1; dst = tWs1; base = id - 48; }
    else              { src = Wn1; dst = tWn1; base = id - 80; }
    int e0 = base * 1024 + threadIdx.x * 4;
    float4 v = *(const float4*)(src + e0);
    int k = e0 >> 7, n = e0 & 127;
    float vv[4] = {v.x, v.y, v.z, v.w};
    int elem = (k & 3) + 4 * ((k >> 4) & 1);
    int g = (k >> 2) & 3;
    int fragkt = (k >> 5) * 8;
#pragma unroll
    for (int i = 0; i < 4; ++i) {
      int nn = n + i;
      int idx = ((fragkt + (nn >> 4)) << 9) + ((g * 16 + (nn & 15)) << 3) + elem;
      dst[idx] = f2bf(vv[i]);
    }
    return;
  }
  // ---- gemm L0: unit = 4 waves/block, 512 units = 256 row-blocks x 2 sets ----
  const int wv = threadIdx.x >> 6, lane = threadIdx.x & 63;
  const int unit = bid * 4 + wv;
  const int set = unit >> 8;
  const int rb = unit & 255;
  const float* W = set ? Ws0 : Wp0;
  const float* bias = set ? bs0 : bp0;
  const int g = lane >> 4, r15 = lane & 15;
  const int row = rb * 16 + r15;
  f32x4 acc[8] = {};
  for (int kt = 0; kt < 256; kt += 32) {
    const float* xp = x + (size_t)row * 256 + kt + 4 * g;
    float4 lo = *(const float4*)xp;
    float4 hi = *(const float4*)(xp + 16);
    short8v a;
    a[0] = (short)f2bf(lo.x); a[1] = (short)f2bf(lo.y);
    a[2] = (short)f2bf(lo.z); a[3] = (short)f2bf(lo.w);
    a[4] = (short)f2bf(hi.x); a[5] = (short)f2bf(hi.y);
    a[6] = (short)f2bf(hi.z); a[7] = (short)f2bf(hi.w);
#pragma unroll
    for (int nf = 0; nf < 8; ++nf) {
      const float* wp = W + (size_t)(kt + 4 * g) * 128 + nf * 16 + r15;
      short8v b;
#pragma unroll
      for (int j = 0; j < 4; ++j) b[j] = (short)f2bf(wp[(size_t)j * 128]);
#pragma unroll
      for (int j = 0; j < 4; ++j) b[4 + j] = (short)f2bf(wp[(size_t)(16 + j) * 128]);
      acc[nf] = __builtin_amdgcn_mfma_f32_16x16x32_bf16(a, b, acc[nf], 0, 0, 0);
    }
  }
#pragma unroll
  for (int nf = 0; nf < 8; ++nf) {
    int col = nf * 16 + r15;
    float bv = bias[col];
#pragma unroll
    for (int r = 0; r < 4; ++r) {
      int orow = rb * 16 + 4 * g + r;
      float t = acc[nf][r] + bv;
      if (set == 0) scores0[(size_t)orow * 128 + col] = f2bf(fmaxf(t, 0.f));
      else          S0[(size_t)orow * 128 + col] = t;
    }
  }
}

// ====== fused per-16-row block: [adj build | adj load] -> gather-max ->
// ======   pool-GEMM + relu + concat-L2norm -> (L0 only) layer-1 dual GEMM ====
template<int LAYER>
__global__ __launch_bounds__(256) void fused(
    const float* __restrict__ A,
    int* __restrict__ cnt_g, unsigned short* __restrict__ nbr_g,
    const unsigned short* __restrict__ scores_in, const float* __restrict__ S_in,
    const unsigned short* __restrict__ tWn, const float* __restrict__ bn,
    const unsigned short* __restrict__ tWp, const float* __restrict__ bp,
    const unsigned short* __restrict__ tWs, const float* __restrict__ bs,
    unsigned short* __restrict__ scores_out, float* __restrict__ S_out,
    float* __restrict__ out) {
  __shared__ int scnt[16];
  __shared__ unsigned short snb[16][CAP];
  __shared__ unsigned short pooled[16][136];
  __shared__ unsigned short xb[16][264];
  __shared__ float ssqw[4][16];
  __shared__ float ssqs[16];
  const int tid = threadIdx.x;
  const int wv = tid >> 6, lane = tid & 63, g = lane >> 4, r15 = lane & 15;
  const int r0 = blockIdx.x * 16;

  if (LAYER == 0) {
    if (tid < 16) scnt[tid] = 0;
    __syncthreads();
    // software-pipelined A scan, 1 row ahead
    const float4* Ar = (const float4*)(A + (size_t)r0 * NN);
    float4 v0 = Ar[tid], v1 = Ar[tid + 256], v2 = Ar[tid + 512], v3 = Ar[tid + 768];
    for (int r = 0; r < 16; ++r) {
      float4 n0, n1, n2, n3;
      if (r < 15) {
        const float4* An = (const float4*)(A + (size_t)(r0 + r + 1) * NN);
        n0 = An[tid]; n1 = An[tid + 256]; n2 = An[tid + 512]; n3 = An[tid + 768];
      }
      int* c = &scnt[r];
      auto proc = [&](float4 v, int j) {
        if (v.x > THRV) { int p = atomicAdd(c, 1); if (p < CAP) snb[r][p] = (unsigned short)j; }
        if (v.y > THRV) { int p = atomicAdd(c, 1); if (p < CAP) snb[r][p] = (unsigned short)(j + 1); }
        if (v.z > THRV) { int p = atomicAdd(c, 1); if (p < CAP) snb[r][p] = (unsigned short)(j + 2); }
        if (v.w > THRV) { int p = atomicAdd(c, 1); if (p < CAP) snb[r][p] = (unsigned short)(j + 3); }
      };
      proc(v0, 4 * tid); proc(v1, 4 * (tid + 256));
      proc(v2, 4 * (tid + 512)); proc(v3, 4 * (tid + 768));
      v0 = n0; v1 = n1; v2 = n2; v3 = n3;
    }
    __syncthreads();
    if (tid < 16) { int c = min(scnt[tid], CAP); scnt[tid] = c; cnt_g[r0 + tid] = c; }
    for (int k2 = tid; k2 < 16 * CAP; k2 += 256)
      nbr_g[(size_t)r0 * CAP + k2] = ((unsigned short*)snb)[k2];
  } else {
    if (tid < 16) scnt[tid] = min(cnt_g[r0 + tid], CAP);
    for (int k2 = tid; k2 < 16 * CAP; k2 += 256)
      ((unsigned short*)snb)[k2] = nbr_g[(size_t)r0 * CAP + k2];
  }
  __syncthreads();

  // ---- gather-max over neighbors (packed u16 max on non-negative bf16) ----
  {
    const int r = tid >> 4, c8 = (tid & 15) * 8;
    const int c = scnt[r];
    uint4 m = make_uint4(0, 0, 0, 0);
    for (int k = 0; k < c; ++k) {
      int j = snb[r][k];
      uint4 v = *(const uint4*)(scores_in + (size_t)j * 128 + c8);
      m.x = maxu16x2(m.x, v.x); m.y = maxu16x2(m.y, v.y);
      m.z = maxu16x2(m.z, v.z); m.w = maxu16x2(m.w, v.w);
    }
    *(uint4*)&pooled[r][c8] = m;
  }
  __syncthreads();

  // ---- self-half relu + partial ssq ----
  const int srow = tid >> 4, sc8 = (tid & 15) * 8;
  float sv[8];
  {
    const float* sp = S_in + (size_t)(r0 + srow) * 128 + sc8;
    float4 sa = *(const float4*)sp;
    float4 sb = *(const float4*)(sp + 4);
    sv[0] = fmaxf(sa.x, 0.f); sv[1] = fmaxf(sa.y, 0.f);
    sv[2] = fmaxf(sa.z, 0.f); sv[3] = fmaxf(sa.w, 0.f);
    sv[4] = fmaxf(sb.x, 0.f); sv[5] = fmaxf(sb.y, 0.f);
    sv[6] = fmaxf(sb.z, 0.f); sv[7] = fmaxf(sb.w, 0.f);
    float ps = 0.f;
#pragma unroll
    for (int i = 0; i < 8; ++i) ps += sv[i] * sv[i];
#pragma unroll
    for (int off = 1; off < 16; off <<= 1) ps += __shfl_xor(ps, off, 16);
    if ((tid & 15) == 0) ssqs[srow] = ps;
  }

  // ---- pool GEMM: pooled[16x128] @ Wn -> 16x128, wave wv owns nf {2wv,2wv+1} ----
  f32x4 pacc[2] = {};
#pragma unroll
  for (int kt = 0; kt < 128; kt += 32) {
    ushort4 alo = *(const ushort4*)&pooled[r15][kt + 4 * g];
    ushort4 ahi = *(const ushort4*)&pooled[r15][kt + 16 + 4 * g];
    short8v a;
    a[0] = alo.x; a[1] = alo.y; a[2] = alo.z; a[3] = alo.w;
    a[4] = ahi.x; a[5] = ahi.y; a[6] = ahi.z; a[7] = ahi.w;
#pragma unroll
    for (int f = 0; f < 2; ++f) {
      int nf = 2 * wv + f;
      uint4 bw = *((const uint4*)(tWn + (size_t)((kt >> 5) * 8 + nf) * 512) + lane);
      short8v b2 = __builtin_bit_cast(short8v, bw);
      pacc[f] = __builtin_amdgcn_mfma_f32_16x16x32_bf16(a, b2, pacc[f], 0, 0, 0);
    }
  }
#pragma unroll
  for (int f = 0; f < 2; ++f) {
    float bv = bn[(2 * wv + f) * 16 + r15];
#pragma unroll
    for (int rr = 0; rr < 4; ++rr) pacc[f][rr] = fmaxf(pacc[f][rr] + bv, 0.f);
  }
#pragma unroll
  for (int rr = 0; rr < 4; ++rr) {
    float ps = pacc[0][rr] * pacc[0][rr] + pacc[1][rr] * pacc[1][rr];
#pragma unroll
    for (int off = 1; off < 16; off <<= 1) ps += __shfl_xor(ps, off, 16);
    if (r15 == 0) ssqw[wv][4 * g + rr] = ps;
  }
  __syncthreads();

  // ---- combine ssq, normalize, write concat row ----
  {
    float tot = ssqs[srow] + ssqw[0][srow] + ssqw[1][srow] + ssqw[2][srow] + ssqw[3][srow];
    float sc = 1.f / fmaxf(sqrtf(tot), 1e-12f);
    if (LAYER == 0) {
      unsigned short h[8];
#pragma unroll
      for (int i = 0; i < 8; ++i) h[i] = f2bf(sv[i] * sc);
      uint4 wvv;
      wvv.x = (unsigned)h[0] | ((unsigned)h[1] << 16);
      wvv.y = (unsigned)h[2] | ((unsigned)h[3] << 16);
      wvv.z = (unsigned)h[4] | ((unsigned)h[5] << 16);
      wvv.w = (unsigned)h[6] | ((unsigned)h[7] << 16);
      *(uint4*)&xb[srow][sc8] = wvv;
    } else {
      float* op = out + (size_t)(r0 + srow) * 256 + sc8;
      *(float4*)op = make_float4(sv[0] * sc, sv[1] * sc, sv[2] * sc, sv[3] * sc);
      *(float4*)(op + 4) = make_float4(sv[4] * sc, sv[5] * sc, sv[6] * sc, sv[7] * sc);
    }
  }
#pragma unroll
  for (int rr = 0; rr < 4; ++rr) {
    int row = 4 * g + rr;
    float tot = ssqs[row] + ssqw[0][row] + ssqw[1][row] + ssqw[2][row] + ssqw[3][row];
    float sc = 1.f / fmaxf(sqrtf(tot), 1e-12f);
#pragma unroll
    for (int f = 0; f < 2; ++f) {
      int col = (2 * wv + f) * 16 + r15;
      float t = pacc[f][rr] * sc;
      if (LAYER == 0) xb[row][128 + col] = f2bf(t);
      else            out[(size_t)(r0 + row) * 256 + 128 + col] = t;
    }
  }

  if (LAYER == 0) {
    __syncthreads();
    // ---- layer-1 dual GEMM on local xb[16][256] ----
    const int s = wv >> 1;                    // 0 -> Wp1/scores1, 1 -> Ws1/S1
    const unsigned short* Wt = s ? tWs : tWp;
    const float* bb = s ? bs : bp;
    const int nf0 = (wv & 1) * 4;
    f32x4 dacc[4] = {};
#pragma unroll
    for (int kt = 0; kt < 256; kt += 32) {
      ushort4 alo = *(const ushort4*)&xb[r15][kt + 4 * g];
      ushort4 ahi = *(const ushort4*)&xb[r15][kt + 16 + 4 * g];
      short8v a;
      a[0] = alo.x; a[1] = alo.y; a[2] = alo.z; a[3] = alo.w;
      a[4] = ahi.x; a[5] = ahi.y; a[6] = ahi.z; a[7] = ahi.w;
#pragma unroll
      for (int f = 0; f < 4; ++f) {
        uint4 bw = *((const uint4*)(Wt + (size_t)((kt >> 5) * 8 + nf0 + f) * 512) + lane);
        short8v b2 = __builtin_bit_cast(short8v, bw);
        dacc[f] = __builtin_amdgcn_mfma_f32_16x16x32_bf16(a, b2, dacc[f], 0, 0, 0);
      }
    }
#pragma unroll
    for (int f = 0; f < 4; ++f) {
      int col = (nf0 + f) * 16 + r15;
      float bv = bb[col];
#pragma unroll
      for (int rr = 0; rr < 4; ++rr) {
        int grow = r0 + 4 * g + rr;
        float t = dacc[f][rr] + bv;
        if (s == 0) scores_out[(size_t)grow * 128 + col] = f2bf(fmaxf(t, 0.f));
        else        S_out[(size_t)grow * 128 + col] = t;
      }
    }
  }
}

extern "C" void kernel_launch(void* const* d_in, const int* in_sizes, int n_in,
                              void* d_out, int out_size, void* d_ws, size_t ws_size,
                              hipStream_t stream) {
  (void)in_sizes; (void)n_in; (void)out_size; (void)ws_size;
  const float* x   = (const float*)d_in[0];
  const float* A   = (const float*)d_in[1];
  const float* Wp0 = (const float*)d_in[2];
  const float* bp0 = (const float*)d_in[3];
  const float* Ws0 = (const float*)d_in[4];
  const float* bs0 = (const float*)d_in[5];
  const float* Wn0 = (const float*)d_in[6];
  const float* bn0 = (const float*)d_in[7];
  const float* Wp1 = (const float*)d_in[8];
  const float* bp1 = (const float*)d_in[9];
  const float* Ws1 = (const float*)d_in[10];
  const float* bs1 = (const float*)d_in[11];
  const float* Wn1 = (const float*)d_in[12];
  const float* bn1 = (const float*)d_in[13];

  char* ws = (char*)d_ws;
  auto alloc = [&](size_t bytes) { char* p = ws; ws += (bytes + 255) & ~(size_t)255; return p; };
  int* cnt             = (int*)alloc((size_t)NN * 4);
  unsigned short* nbr  = (unsigned short*)alloc((size_t)NN * CAP * 2);
  unsigned short* tWn0 = (unsigned short*)alloc(128 * 128 * 2);
  unsigned short* tWp1 = (unsigned short*)alloc(256 * 128 * 2);
  unsigned short* tWs1 = (unsigned short*)alloc(256 * 128 * 2);
  unsigned short* tWn1 = (unsigned short*)alloc(128 * 128 * 2);
  unsigned short* scores0 = (unsigned short*)alloc((size_t)NN * 128 * 2);
  float* S0            = (float*)alloc((size_t)NN * 128 * 4);
  unsigned short* scores1 = (unsigned short*)alloc((size_t)NN * 128 * 2);
  float* S1            = (float*)alloc((size_t)NN * 128 * 4);

  k1<<<224, 256, 0, stream>>>(x, Wp0, bp0, Ws0, bs0, Wn0, Wp1, Ws1, Wn1,
                              scores0, S0, tWn0, tWp1, tWs1, tWn1);
  fused<0><<<NN / 16, 256, 0, stream>>>(A, cnt, nbr, scores0, S0,
                                        tWn0, bn0, tWp1, bp1, tWs1, bs1,
                                        scores1, S1, nullptr);
  fused<1><<<NN / 16, 256, 0, stream>>>(A, cnt, nbr, scores1, S1,
                                        tWn1, bn1, nullptr, nullptr, nullptr, nullptr,
                                        nullptr, nullptr, (float*)d_out);
}